// Round 21
// baseline (36.402 us; speedup 1.0000x reference)
//
#include <hip/hip_runtime.h>

#define H 512
#define W 512
#define BAND 64
#define NBANDS (H / BAND)   // 8
#define NEG_INF (-3.402823466e38f)

__global__ void zero_acc_kernel(double* acc) {
    if (threadIdx.x == 0) acc[0] = 0.0;
}

// DPP wave shifts: wave_shr1 (0x138) = shfl_up by 1 (old = lane-0 fill);
// wave_shl1 (0x130) = shfl_down by 1 (old = lane-63 fill). Pure VALU.
__device__ __forceinline__ float dpp_up1(float x, float fill) {
    return __int_as_float(__builtin_amdgcn_update_dpp(
        __float_as_int(fill), __float_as_int(x), 0x138, 0xF, 0xF, false));
}
__device__ __forceinline__ float dpp_down1(float x, float fill) {
    return __int_as_float(__builtin_amdgcn_update_dpp(
        __float_as_int(fill), __float_as_int(x), 0x130, 0xF, 0xF, false));
}

// R20 structure (best: 31.9us) + R21: register prefetch of next batch's two
// MIDDLE rows (the only compulsory loads: each pair's halo rows j0-1/j1+1 are
// sibling waves' middle rows -> L1/L2 hits) + raw s_barrier WITHOUT vmcnt
// drain (lgkmcnt(0) only) so prefetch loads ride across the barrier to their
// consume in the next iteration (~full batch of cover for L3/HBM latency).
// R18 lesson: dummy-LDS prefetch duplicated FETCH and was drained at the
// __syncthreads vmcnt(0) -> reg-destined loads + raw barrier avoid both.
// All prefetch state in named float4s, copies at iteration end (regalloc
// coalesces; no dynamic indexing -> no scratch, rule verified R12/R13).
__global__ __launch_bounds__(512, 4) void fused_kernel(const float* __restrict__ in0,
                                                       const float* __restrict__ in1,
                                                       double* __restrict__ acc) {
    const int band = blockIdx.x;
    const int img  = blockIdx.y;
    const float* __restrict__ im = (blockIdx.z ? in1 : in0) + (size_t)img * H * W;

    const int y0 = band * BAND, y1 = y0 + BAND;
    const int jlo_v = y0 - 8;            // first streamed s-row (even)

    __shared__ float hbuf[2][16][W];     // double-buffered h rows (split-half)
    __shared__ double wsum[8];

    const int tid  = threadIdx.x;
    const int w    = tid >> 6;           // wave id 0..7
    const int lane = tid & 63;
    const int c0   = lane << 3;          // 8 cols per lane
    // split-half position of column tid inside an hbuf row
    const int pos  = ((tid & 4) ? 256 : 0) + ((tid >> 3) << 2) + (tid & 3);

    float accMax = 0.f, accSum = 0.f;
    float arr[16];                       // van Herk: prev-seg suffix / cur h

// Per-row tail: from t[8] (3-row raw sum) compute s, accSum, h, write hbuf.
#define ROWTAIL(T, J, SLOT)                                                    \
    {                                                                          \
        const float tl = dpp_up1((T)[7], 0.f);                                 \
        const float tr = dpp_down1((T)[0], 0.f);                               \
        float s[8];                                                            \
        s[0] = tl + (T)[0] + (T)[1];                                           \
        _Pragma("unroll") for (int k = 1; k < 7; ++k)                          \
            s[k] = (T)[k - 1] + (T)[k] + (T)[k + 1];                           \
        s[7] = (T)[6] + (T)[7] + tr;                                           \
        const int rlo = ((J) - 8 > y0) ? (J) - 8 : y0;                         \
        const int rhi = ((J) + 8 < y1 - 1) ? (J) + 8 : y1 - 1;                 \
        float rowsum = 0.f;                                                    \
        _Pragma("unroll") for (int k = 0; k < 8; ++k) {                        \
            const int col = c0 + k;                                            \
            const int wlo = (col - 8 > 0) ? col - 8 : 0;                       \
            const int whi = (col + 8 < W - 1) ? col + 8 : W - 1;               \
            rowsum += s[k] * (float)(whi - wlo + 1);                           \
        }                                                                      \
        accSum += rowsum * ((float)(rhi - rlo + 1) * (1.f / 289.f));           \
        float p[8], qarr[8];                                                   \
        p[0] = s[0];                                                           \
        _Pragma("unroll") for (int k = 1; k < 8; ++k)                          \
            p[k] = fmaxf(p[k - 1], s[k]);                                      \
        qarr[7] = s[7];                                                        \
        _Pragma("unroll") for (int k = 6; k >= 0; --k)                         \
            qarr[k] = fmaxf(qarr[k + 1], s[k]);                                \
        const float m = p[7];                                                  \
        float h[8];                                                            \
        _Pragma("unroll") for (int k = 0; k < 8; ++k) {                        \
            const float qp = dpp_up1(qarr[k], NEG_INF);                        \
            const float pn = dpp_down1(p[k], NEG_INF);                         \
            h[k] = fmaxf(fmaxf(qp, m), pn);                                    \
        }                                                                      \
        float* hw = hwbase + (SLOT) * W;                                       \
        *(float4*)&hw[lane << 2]         = make_float4(h[0], h[1], h[2], h[3]); \
        *(float4*)&hw[256 + (lane << 2)] = make_float4(h[4], h[5], h[6], h[7]); \
    }

    // ---- prologue: prefetch batch 0's middle rows (clamped addresses) ----
    float4 pa, pb, pc, pd;
    {
        int r0 = jlo_v + 2 * w;     r0 = r0 < 0 ? 0 : (r0 > H - 1 ? H - 1 : r0);
        int r1 = jlo_v + 2 * w + 1; r1 = r1 < 0 ? 0 : (r1 > H - 1 ? H - 1 : r1);
        const float* rp = im + (size_t)r0 * W + c0;
        pa = *(const float4*)rp;  pb = *(const float4*)(rp + 4);
        const float* rq = im + (size_t)r1 * W + c0;
        pc = *(const float4*)rq;  pd = *(const float4*)(rq + 4);
    }

#pragma unroll 1
    for (int b = 0; b < 5; ++b) {        // 5 batches of 16 s-rows = 80 rows
        const int jb = jlo_v + b * 16;
        float* hwbase = &hbuf[b & 1][0][0];
        const int j0 = jb + 2 * w;       // wave's contiguous pair (j0 even)
        const int j1 = j0 + 1;

        // ---- issue next batch's middle-row loads (consumed next iter) ----
        float4 na, nb, nc, nd;
        {
            int r0 = j0 + 16; r0 = r0 < 0 ? 0 : (r0 > H - 1 ? H - 1 : r0);
            int r1 = j1 + 16; r1 = r1 < 0 ? 0 : (r1 > H - 1 ? H - 1 : r1);
            const float* rp = im + (size_t)r0 * W + c0;
            na = *(const float4*)rp;  nb = *(const float4*)(rp + 4);
            const float* rq = im + (size_t)r1 * W + c0;
            nc = *(const float4*)rq;  nd = *(const float4*)(rq + 4);
        }

        if (j0 >= 0 && j0 < H) {         // pair entirely real (never straddles)
            // halo rows (sibling waves' middle rows -> L1/L2 hits)
            float v0[8], v3[8];
            if (j0 - 1 >= 0) {
                const float* rp = im + (size_t)(j0 - 1) * W + c0;
                const float4 a = *(const float4*)rp;
                const float4 c4 = *(const float4*)(rp + 4);
                v0[0]=a.x; v0[1]=a.y; v0[2]=a.z; v0[3]=a.w;
                v0[4]=c4.x; v0[5]=c4.y; v0[6]=c4.z; v0[7]=c4.w;
            } else {
#pragma unroll
                for (int k = 0; k < 8; ++k) v0[k] = 0.f;
            }
            if (j1 + 1 < H) {
                const float* rp = im + (size_t)(j1 + 1) * W + c0;
                const float4 a = *(const float4*)rp;
                const float4 c4 = *(const float4*)(rp + 4);
                v3[0]=a.x; v3[1]=a.y; v3[2]=a.z; v3[3]=a.w;
                v3[4]=c4.x; v3[5]=c4.y; v3[6]=c4.z; v3[7]=c4.w;
            } else {
#pragma unroll
                for (int k = 0; k < 8; ++k) v3[k] = 0.f;
            }
            // middle rows from prefetch regs
            const float v1[8] = {pa.x, pa.y, pa.z, pa.w, pb.x, pb.y, pb.z, pb.w};
            const float v2[8] = {pc.x, pc.y, pc.z, pc.w, pd.x, pd.y, pd.z, pd.w};
            float t0[8], t1[8];
#pragma unroll
            for (int k = 0; k < 8; ++k) {
                const float mid = v1[k] + v2[k];
                t0[k] = v0[k] + mid;
                t1[k] = mid + v3[k];
            }
            ROWTAIL(t0, j0, 2 * w)
            ROWTAIL(t1, j1, 2 * w + 1)
        } else {                         // virtual pair
            const float4 ninf = make_float4(NEG_INF, NEG_INF, NEG_INF, NEG_INF);
            float* hw = hwbase + (2 * w) * W;
            *(float4*)&hw[lane << 2]         = ninf;
            *(float4*)&hw[256 + (lane << 2)] = ninf;
            hw += W;
            *(float4*)&hw[lane << 2]         = ninf;
            *(float4*)&hw[256 + (lane << 2)] = ninf;
        }

        // rotate prefetch regs (regalloc coalesces; vmcnt wait lands at the
        // first USE next iteration, not here)
        pa = na; pb = nb; pc = nc; pd = nd;

        // raw barrier: drain LDS writes only; prefetch vmcnt stays in flight
        asm volatile("s_waitcnt lgkmcnt(0)" ::: "memory");
        __builtin_amdgcn_s_barrier();

        // ---- stage C: vertical van Herk over this 16-row segment ----
        const float* hb = hwbase;
        float Pblk = NEG_INF;
        if (b >= 1) {
#pragma unroll
            for (int r = 0; r < 16; ++r) {
                const float hv = hb[r * W + pos];
                Pblk = fmaxf(Pblk, hv);
                accMax += fmaxf(arr[r], Pblk);
                arr[r] = hv;
            }
        } else {
#pragma unroll
            for (int r = 0; r < 16; ++r) {
                const float hv = hb[r * W + pos];
                Pblk = fmaxf(Pblk, hv);
                arr[r] = hv;
            }
        }
        // segment end: in-place suffix transform arr[r] = max(h[r..15])
#pragma unroll
        for (int rr = 14; rr >= 0; --rr) arr[rr] = fmaxf(arr[rr], arr[rr + 1]);
    }
#undef ROWTAIL

    // ---- block reduction (values are 9x-scaled; undo once) ----
    double v = ((double)accMax - (double)accSum) * (1.0 / 9.0);
#pragma unroll
    for (int off = 32; off > 0; off >>= 1) v += __shfl_down(v, off, 64);
    if (lane == 0) wsum[w] = v;
    __syncthreads();
    if (tid == 0) {
        double bsum = 0.0;
#pragma unroll
        for (int wv = 0; wv < 8; ++wv) bsum += wsum[wv];
        atomicAdd(acc, bsum);
    }
}

__global__ void finalize_kernel(const double* __restrict__ acc, float* __restrict__ out) {
    if (threadIdx.x == 0) {
        // total pixels across both tensors = 2*32*512*512 = 16777216
        out[0] = (float)(1.0 - acc[0] * (1.0 / 16777216.0));
    }
}

extern "C" void kernel_launch(void* const* d_in, const int* in_sizes, int n_in,
                              void* d_out, int out_size, void* d_ws, size_t ws_size,
                              hipStream_t stream) {
    const float* in0 = (const float*)d_in[0];
    const float* in1 = (const float*)d_in[1];
    float* out = (float*)d_out;
    double* acc = (double*)d_ws;

    zero_acc_kernel<<<1, 64, 0, stream>>>(acc);
    fused_kernel<<<dim3(NBANDS, 32, 2), 512, 0, stream>>>(in0, in1, acc);
    finalize_kernel<<<1, 64, 0, stream>>>(acc, out);
}

// Round 22
// 24.933 us; speedup vs baseline: 1.4600x; 1.4600x over previous
//
#include <hip/hip_runtime.h>

#define H 512
#define W 512
#define BAND 64
#define NBANDS (H / BAND)   // 8
#define NBLK (NBANDS * 32 * 2)  // 512 blocks
#define NEG_INF (-3.402823466e38f)

// DPP wave shifts: wave_shr1 (0x138) = shfl_up by 1 (old = lane-0 fill);
// wave_shl1 (0x130) = shfl_down by 1 (old = lane-63 fill). Pure VALU.
__device__ __forceinline__ float dpp_up1(float x, float fill) {
    return __int_as_float(__builtin_amdgcn_update_dpp(
        __float_as_int(fill), __float_as_int(x), 0x138, 0xF, 0xF, false));
}
__device__ __forceinline__ float dpp_down1(float x, float fill) {
    return __int_as_float(__builtin_amdgcn_update_dpp(
        __float_as_int(fill), __float_as_int(x), 0x130, 0xF, 0xF, false));
}

// R20 structure (best: 31.9us) + R22: (a) per-block partials (plain store,
// no zero-kernel, no atomic -> one fewer launch in the graph); (b) 1D grid
// with id = band*64 + (img*2+tensor): id%8 (XCD heuristic) constant across
// all 8 bands of an (img,tensor) -> 16-row halos between adjacent bands hit
// the same XCD's L2 instead of re-fetching HBM.
// Proven core (R19/R20): batches of 16 s-rows; wave owns contiguous pair
// (2w, 2w+1): 8 float4 loads/pair (shared halo rows), shared middle partial;
// s = 3-sum via 2 DPP halos (9x-scaled); horizontal 17-max via suffix q[8] /
// prefix p[8] + 16 DPP shifts: h(8L+k) = max(q_{L-1}[k], m_L, p_{L+1}[k]);
// vertical 17-max: batch == van Herk segment, h rows -> double-buffered hbuf
// (ONE __syncthreads per batch), per-column register van Herk (arr[16]).
// Lessons: (R12/R13) unroll-hoisting/tight-cap spills -> `#pragma unroll 1`
// + (512,4); (R16) extra barrier regressed; (R18/R21) both prefetch forms
// INCREASED FETCH (41->66/68MB, lines evicted before use) and regressed ->
// no prefetch. hbuf split-half layout: k=0..3 at [4L], k=4..7 at [256+4L];
// writes and column reads conflict-free.
__global__ __launch_bounds__(512, 4) void fused_kernel(const float* __restrict__ in0,
                                                       const float* __restrict__ in1,
                                                       double* __restrict__ partial) {
    const int id   = blockIdx.x;
    const int band = id >> 6;            // 0..7
    const int u    = id & 63;            // (img*2 + tensor)
    const int img  = u >> 1;
    const float* __restrict__ im = ((u & 1) ? in1 : in0) + (size_t)img * H * W;

    const int y0 = band * BAND, y1 = y0 + BAND;
    const int jlo_v = y0 - 8;            // first streamed s-row (even)

    __shared__ float hbuf[2][16][W];     // double-buffered h rows (split-half)
    __shared__ double wsum[8];

    const int tid  = threadIdx.x;
    const int w    = tid >> 6;           // wave id 0..7
    const int lane = tid & 63;
    const int c0   = lane << 3;          // 8 cols per lane
    // split-half position of column tid inside an hbuf row
    const int pos  = ((tid & 4) ? 256 : 0) + ((tid >> 3) << 2) + (tid & 3);

    float accMax = 0.f, accSum = 0.f;
    float arr[16];                       // van Herk: prev-seg suffix / cur h

// Per-row tail: from t[8] (3-row raw sum) compute s, accSum, h, write hbuf.
#define ROWTAIL(T, J, SLOT)                                                    \
    {                                                                          \
        const float tl = dpp_up1((T)[7], 0.f);                                 \
        const float tr = dpp_down1((T)[0], 0.f);                               \
        float s[8];                                                            \
        s[0] = tl + (T)[0] + (T)[1];                                           \
        _Pragma("unroll") for (int k = 1; k < 7; ++k)                          \
            s[k] = (T)[k - 1] + (T)[k] + (T)[k + 1];                           \
        s[7] = (T)[6] + (T)[7] + tr;                                           \
        const int rlo = ((J) - 8 > y0) ? (J) - 8 : y0;                         \
        const int rhi = ((J) + 8 < y1 - 1) ? (J) + 8 : y1 - 1;                 \
        float rowsum = 0.f;                                                    \
        _Pragma("unroll") for (int k = 0; k < 8; ++k) {                        \
            const int col = c0 + k;                                            \
            const int wlo = (col - 8 > 0) ? col - 8 : 0;                       \
            const int whi = (col + 8 < W - 1) ? col + 8 : W - 1;               \
            rowsum += s[k] * (float)(whi - wlo + 1);                           \
        }                                                                      \
        accSum += rowsum * ((float)(rhi - rlo + 1) * (1.f / 289.f));           \
        float p[8], qarr[8];                                                   \
        p[0] = s[0];                                                           \
        _Pragma("unroll") for (int k = 1; k < 8; ++k)                          \
            p[k] = fmaxf(p[k - 1], s[k]);                                      \
        qarr[7] = s[7];                                                        \
        _Pragma("unroll") for (int k = 6; k >= 0; --k)                         \
            qarr[k] = fmaxf(qarr[k + 1], s[k]);                                \
        const float m = p[7];                                                  \
        float h[8];                                                            \
        _Pragma("unroll") for (int k = 0; k < 8; ++k) {                        \
            const float qp = dpp_up1(qarr[k], NEG_INF);                        \
            const float pn = dpp_down1(p[k], NEG_INF);                         \
            h[k] = fmaxf(fmaxf(qp, m), pn);                                    \
        }                                                                      \
        float* hw = hwbase + (SLOT) * W;                                       \
        *(float4*)&hw[lane << 2]         = make_float4(h[0], h[1], h[2], h[3]); \
        *(float4*)&hw[256 + (lane << 2)] = make_float4(h[4], h[5], h[6], h[7]); \
    }

#pragma unroll 1
    for (int b = 0; b < 5; ++b) {        // 5 batches of 16 s-rows = 80 rows
        const int jb = jlo_v + b * 16;
        float* hwbase = &hbuf[b & 1][0][0];

        const int j0 = jb + 2 * w;       // wave's contiguous pair (j0 even)
        const int j1 = j0 + 1;
        if (j0 >= 0 && j0 < H) {         // pair entirely real (never straddles)
            // ---- shared loads: raw rows j0-1 .. j0+2 (4 rows, 8 float4) ----
            float v0[8], v1[8], v2[8], v3[8];
            {
                const float* rp = im + (size_t)j0 * W + c0;        // row j0
                const float4 a = *(const float4*)rp;
                const float4 c4 = *(const float4*)(rp + 4);
                v1[0]=a.x; v1[1]=a.y; v1[2]=a.z; v1[3]=a.w;
                v1[4]=c4.x; v1[5]=c4.y; v1[6]=c4.z; v1[7]=c4.w;
            }
            {
                const float* rp = im + (size_t)j1 * W + c0;        // row j1
                const float4 a = *(const float4*)rp;
                const float4 c4 = *(const float4*)(rp + 4);
                v2[0]=a.x; v2[1]=a.y; v2[2]=a.z; v2[3]=a.w;
                v2[4]=c4.x; v2[5]=c4.y; v2[6]=c4.z; v2[7]=c4.w;
            }
            if (j0 - 1 >= 0) {
                const float* rp = im + (size_t)(j0 - 1) * W + c0;  // row j0-1
                const float4 a = *(const float4*)rp;
                const float4 c4 = *(const float4*)(rp + 4);
                v0[0]=a.x; v0[1]=a.y; v0[2]=a.z; v0[3]=a.w;
                v0[4]=c4.x; v0[5]=c4.y; v0[6]=c4.z; v0[7]=c4.w;
            } else {
#pragma unroll
                for (int k = 0; k < 8; ++k) v0[k] = 0.f;
            }
            if (j1 + 1 < H) {
                const float* rp = im + (size_t)(j1 + 1) * W + c0;  // row j1+1
                const float4 a = *(const float4*)rp;
                const float4 c4 = *(const float4*)(rp + 4);
                v3[0]=a.x; v3[1]=a.y; v3[2]=a.z; v3[3]=a.w;
                v3[4]=c4.x; v3[5]=c4.y; v3[6]=c4.z; v3[7]=c4.w;
            } else {
#pragma unroll
                for (int k = 0; k < 8; ++k) v3[k] = 0.f;
            }
            // ---- shared middle partial: t0 = v0+v1+v2, t1 = v1+v2+v3 ----
            float t0[8], t1[8];
#pragma unroll
            for (int k = 0; k < 8; ++k) {
                const float mid = v1[k] + v2[k];
                t0[k] = v0[k] + mid;
                t1[k] = mid + v3[k];
            }
            ROWTAIL(t0, j0, 2 * w)
            ROWTAIL(t1, j1, 2 * w + 1)
        } else {                         // virtual pair
            const float4 ninf = make_float4(NEG_INF, NEG_INF, NEG_INF, NEG_INF);
            float* hw = hwbase + (2 * w) * W;
            *(float4*)&hw[lane << 2]         = ninf;
            *(float4*)&hw[256 + (lane << 2)] = ninf;
            hw += W;
            *(float4*)&hw[lane << 2]         = ninf;
            *(float4*)&hw[256 + (lane << 2)] = ninf;
        }
        __syncthreads();                  // the ONLY barrier per batch

        // ---- stage C: vertical van Herk over this 16-row segment ----
        const float* hb = hwbase;
        float Pblk = NEG_INF;
        if (b >= 1) {
#pragma unroll
            for (int r = 0; r < 16; ++r) {
                const float hv = hb[r * W + pos];
                Pblk = fmaxf(Pblk, hv);
                accMax += fmaxf(arr[r], Pblk);
                arr[r] = hv;
            }
        } else {
#pragma unroll
            for (int r = 0; r < 16; ++r) {
                const float hv = hb[r * W + pos];
                Pblk = fmaxf(Pblk, hv);
                arr[r] = hv;
            }
        }
        // segment end: in-place suffix transform arr[r] = max(h[r..15])
#pragma unroll
        for (int rr = 14; rr >= 0; --rr) arr[rr] = fmaxf(arr[rr], arr[rr + 1]);
    }
#undef ROWTAIL

    // ---- block reduction -> per-block partial (plain store, no atomic) ----
    double v = ((double)accMax - (double)accSum) * (1.0 / 9.0);
#pragma unroll
    for (int off = 32; off > 0; off >>= 1) v += __shfl_down(v, off, 64);
    if (lane == 0) wsum[w] = v;
    __syncthreads();
    if (tid == 0) {
        double bsum = 0.0;
#pragma unroll
        for (int wv = 0; wv < 8; ++wv) bsum += wsum[wv];
        partial[id] = bsum;              // written every call: deterministic
    }
}

__global__ __launch_bounds__(512) void finalize_kernel(const double* __restrict__ partial,
                                                       float* __restrict__ out) {
    __shared__ double wsum[8];
    const int tid = threadIdx.x;
    double v = partial[tid];             // 512 partials, one per block
#pragma unroll
    for (int off = 32; off > 0; off >>= 1) v += __shfl_down(v, off, 64);
    if ((tid & 63) == 0) wsum[tid >> 6] = v;
    __syncthreads();
    if (tid == 0) {
        double s = 0.0;
#pragma unroll
        for (int wv = 0; wv < 8; ++wv) s += wsum[wv];
        // total pixels across both tensors = 2*32*512*512 = 16777216
        out[0] = (float)(1.0 - s * (1.0 / 16777216.0));
    }
}

extern "C" void kernel_launch(void* const* d_in, const int* in_sizes, int n_in,
                              void* d_out, int out_size, void* d_ws, size_t ws_size,
                              hipStream_t stream) {
    const float* in0 = (const float*)d_in[0];
    const float* in1 = (const float*)d_in[1];
    float* out = (float*)d_out;
    double* partial = (double*)d_ws;     // 512 doubles = 4 KB

    fused_kernel<<<NBLK, 512, 0, stream>>>(in0, in1, partial);
    finalize_kernel<<<1, 512, 0, stream>>>(partial, out);
}